// Round 16
// baseline (56.117 us; speedup 1.0000x reference)
//
#include <hip/hip_runtime.h>

// out = atoms_x - segment_mean(atoms_x, graph_batch)[graph_batch], gb SORTED.
// r15 structure (4 indep waves/WG, CPT=8, hoisted halos, per-lane run accum
// -> per-wave LDS slot table). SINGLE DELTA vs r15: the store path.
//   Chunked result regs -> LDS rows of 28 words (7 quads: chunked b128
//   writes hit quad-banks (j-l)%8, conflict-free per 8-lane phase) ->
//   dense b128 reads -> NON-TEMPORAL dense stores (each instr = 16 FULL
//   64B lines -> no r6 write amplification; out bypasses L3 so the 128MB
//   of inputs stays L3-resident across graph replays -> FETCH collapses).

typedef float f32x4 __attribute__((ext_vector_type(4)));

static constexpr int WAVE   = 64;
static constexpr int WPB    = 4;                 // independent waves / WG
static constexpr int TPB    = WAVE * WPB;
static constexpr int CPT    = 8;                 // atoms per lane
static constexpr int WCHUNK = WAVE * CPT;        // 512 atoms per wave
static constexpr int SLOTS  = 64;                // id-span per chunk (exp ~13)
static constexpr int ROWW   = 28;                // padded words per lane row

#define LDS_FENCE() asm volatile("s_waitcnt lgkmcnt(0)" ::: "memory")

__device__ void serial_fallback(const float* __restrict__ x,
                                const int* __restrict__ gb,
                                float* __restrict__ out, int n,
                                long long cs, long long ce, int lane) {
  // Pathological id-sparsity; wave-uniform, never hot, correct.
  if (lane != 0) return;
  long long i = cs;
  while (i < ce) {
    int id = gb[i];
    long long rs = i; while (rs > 0 && gb[rs - 1] == id) --rs;
    long long re = i; while (re < n && gb[re] == id) ++re;
    float sx = 0.f, sy = 0.f, sz = 0.f;
    for (long long k = rs; k < re; ++k) {
      sx += x[k * 3 + 0]; sy += x[k * 3 + 1]; sz += x[k * 3 + 2];
    }
    float inv = 1.f / (float)(re - rs);
    float mx = sx * inv, my = sy * inv, mz = sz * inv;
    long long we = (re < ce) ? re : ce;
    for (long long k = i; k < we; ++k) {
      out[k * 3 + 0] = x[k * 3 + 0] - mx;
      out[k * 3 + 1] = x[k * 3 + 1] - my;
      out[k * 3 + 2] = x[k * 3 + 2] - mz;
    }
    i = we;
  }
}

__global__ __launch_bounds__(TPB) void fused_center_kernel(
    const float* __restrict__ x, const int* __restrict__ gb,
    float* __restrict__ out, int n) {
  __shared__ float sums_all[WPB][SLOTS * 4];      // 1 KB / wave
  __shared__ alignas(16) float obuf_all[WPB][WAVE * ROWW];  // 7 KB / wave

  const int w = threadIdx.x >> 6;
  const int lane = threadIdx.x & 63;
  float* sums = sums_all[w];
  float* obuf = obuf_all[w];

  const long long cs = ((long long)blockIdx.x * WPB + w) * WCHUNK;
  if (cs >= (long long)n) return;  // idle wave; no barriers anywhere
  const long long ce = (cs + WCHUNK < (long long)n) ? cs + WCHUNK : (long long)n;

  if (ce - cs < WCHUNK) {
    // ---- partial tail chunk (at most one wave in the grid) ----
    const int fid = gb[cs];
    const int lid = gb[ce - 1];
    const int span = lid - fid + 1;
    if (span > SLOTS) { serial_fallback(x, gb, out, n, cs, ce, lane); return; }
    for (int s = lane; s < span * 4; s += WAVE) sums[s] = 0.f;
    LDS_FENCE();
    for (long long i = cs + lane; i < ce; i += WAVE) {
      int s = (gb[i] - fid) * 4;
      atomicAdd(&sums[s + 0], x[i * 3 + 0]);
      atomicAdd(&sums[s + 1], x[i * 3 + 1]);
      atomicAdd(&sums[s + 2], x[i * 3 + 2]);
      atomicAdd(&sums[s + 3], 1.f);
    }
    if (cs > 0) {  // front halo only (ce == n here)
      float hx = 0.f, hy = 0.f, hz = 0.f, hc = 0.f;
      long long off = 1 + lane;
      for (;;) {
        long long i = cs - off;
        bool m = (i >= 0) && (gb[i] == fid);
        if (m) { hx += x[i*3+0]; hy += x[i*3+1]; hz += x[i*3+2]; hc += 1.f; }
        if (__popcll(__ballot(m)) < WAVE) break;
        off += WAVE;
      }
#pragma unroll
      for (int d = 1; d < 64; d <<= 1) {
        hx += __shfl_xor(hx, d); hy += __shfl_xor(hy, d);
        hz += __shfl_xor(hz, d); hc += __shfl_xor(hc, d);
      }
      if (lane == 0 && hc > 0.f) {
        atomicAdd(&sums[0], hx); atomicAdd(&sums[1], hy);
        atomicAdd(&sums[2], hz); atomicAdd(&sums[3], hc);
      }
    }
    LDS_FENCE();
    for (int s = lane; s < span; s += WAVE) {
      float c = sums[s * 4 + 3];
      if (c > 0.f) {
        float inv = 1.f / c;
        sums[s*4+0] *= inv; sums[s*4+1] *= inv; sums[s*4+2] *= inv;
      }
    }
    LDS_FENCE();
    for (long long i = cs + lane; i < ce; i += WAVE) {
      int s = (gb[i] - fid) * 4;
      out[i * 3 + 0] = x[i * 3 + 0] - sums[s + 0];
      out[i * 3 + 1] = x[i * 3 + 1] - sums[s + 1];
      out[i * 3 + 2] = x[i * 3 + 2] - sums[s + 2];
    }
    return;
  }

  const long long base = cs + (long long)lane * CPT;

  // ---- main load burst (chunked float4/int4; regular loads -> L3 keeps them) ----
  float f[CPT * 3];
  int ids[CPT];
  {
    const float4* xv = reinterpret_cast<const float4*>(x + base * 3);
#pragma unroll
    for (int j = 0; j < CPT * 3 / 4; ++j) {
      float4 v = xv[j];
      f[j * 4 + 0] = v.x; f[j * 4 + 1] = v.y;
      f[j * 4 + 2] = v.z; f[j * 4 + 3] = v.w;
    }
    const int4* gv = reinterpret_cast<const int4*>(gb + base);
#pragma unroll
    for (int j = 0; j < CPT / 4; ++j) {
      int4 g = gv[j];
      ids[j * 4 + 0] = g.x; ids[j * 4 + 1] = g.y;
      ids[j * 4 + 2] = g.z; ids[j * 4 + 3] = g.w;
    }
  }

  // ---- HOISTED halo probes (issued with the main burst) ----
  const bool hasF = (cs > 0);
  const bool hasB = (ce < (long long)n);
  int pf = -1, pb = -1;
  if (hasF) pf = gb[cs - 1 - lane];
  if (hasB && ce + lane < (long long)n) pb = gb[ce + lane];

  // zero slot table (one float4 per lane)
  reinterpret_cast<float4*>(sums)[lane] = make_float4(0.f, 0.f, 0.f, 0.f);
  LDS_FENCE();

  const int fid = __shfl(ids[0], 0);
  const int lid = __shfl(ids[CPT - 1], WAVE - 1);
  const int span = lid - fid + 1;
  if (span > SLOTS) { serial_fallback(x, gb, out, n, cs, ce, lane); return; }

  // ---- masked x-halo loads BEFORE the accumulate (latency hidden) ----
  const bool mf = hasF && (pf == fid);
  const bool mb = hasB && (pb == lid);
  float fhx = 0.f, fhy = 0.f, fhz = 0.f, fhc = 0.f;
  if (mf) {
    long long i = cs - 1 - lane;
    fhx = x[i * 3 + 0]; fhy = x[i * 3 + 1]; fhz = x[i * 3 + 2]; fhc = 1.f;
  }
  float bhx = 0.f, bhy = 0.f, bhz = 0.f, bhc = 0.f;
  if (mb) {
    long long i = ce + lane;
    bhx = x[i * 3 + 0]; bhy = x[i * 3 + 1]; bhz = x[i * 3 + 2]; bhc = 1.f;
  }

  // ---- per-lane run accumulation, flush at id boundaries ----
  {
    int cur = ids[0];
    float sx = 0.f, sy = 0.f, sz = 0.f, sc = 0.f;
#pragma unroll
    for (int j = 0; j < CPT; ++j) {
      if (ids[j] != cur) {
        int s = (cur - fid) * 4;
        atomicAdd(&sums[s + 0], sx); atomicAdd(&sums[s + 1], sy);
        atomicAdd(&sums[s + 2], sz); atomicAdd(&sums[s + 3], sc);
        cur = ids[j]; sx = sy = sz = sc = 0.f;
      }
      sx += f[j * 3 + 0]; sy += f[j * 3 + 1]; sz += f[j * 3 + 2]; sc += 1.f;
    }
    int s = (cur - fid) * 4;
    atomicAdd(&sums[s + 0], sx); atomicAdd(&sums[s + 1], sy);
    atomicAdd(&sums[s + 2], sz); atomicAdd(&sums[s + 3], sc);
  }

  // ---- front halo: continuation (rare: run >= 64) + reduce + flush ----
  if (hasF) {
    unsigned long long bal = __ballot(mf);
    long long off = (long long)WAVE + 1 + lane;
    while (__popcll(bal) == WAVE) {
      long long i = cs - off;
      bool m2 = (i >= 0) && (gb[i] == fid);
      if (m2) {
        fhx += x[i*3+0]; fhy += x[i*3+1]; fhz += x[i*3+2]; fhc += 1.f;
      }
      bal = __ballot(m2);
      off += WAVE;
    }
#pragma unroll
    for (int d = 1; d < 64; d <<= 1) {
      fhx += __shfl_xor(fhx, d); fhy += __shfl_xor(fhy, d);
      fhz += __shfl_xor(fhz, d); fhc += __shfl_xor(fhc, d);
    }
    if (lane == 0 && fhc > 0.f) {
      atomicAdd(&sums[0], fhx); atomicAdd(&sums[1], fhy);
      atomicAdd(&sums[2], fhz); atomicAdd(&sums[3], fhc);
    }
  }
  // ---- back halo ----
  if (hasB) {
    unsigned long long bal = __ballot(mb);
    long long off = (long long)WAVE + lane;
    while (__popcll(bal) == WAVE) {
      long long i = ce + off;
      bool m2 = (i < (long long)n) && (gb[i] == lid);
      if (m2) {
        bhx += x[i*3+0]; bhy += x[i*3+1]; bhz += x[i*3+2]; bhc += 1.f;
      }
      bal = __ballot(m2);
      off += WAVE;
    }
#pragma unroll
    for (int d = 1; d < 64; d <<= 1) {
      bhx += __shfl_xor(bhx, d); bhy += __shfl_xor(bhy, d);
      bhz += __shfl_xor(bhz, d); bhc += __shfl_xor(bhc, d);
    }
    if (lane == 0 && bhc > 0.f) {
      int s = (lid - fid) * 4;
      atomicAdd(&sums[s + 0], bhx); atomicAdd(&sums[s + 1], bhy);
      atomicAdd(&sums[s + 2], bhz); atomicAdd(&sums[s + 3], bhc);
    }
  }
  LDS_FENCE();

  // ---- sums -> means (span <= 64: one slot per lane) ----
  if (lane < span) {
    float c = sums[lane * 4 + 3];
    if (c > 0.f) {
      float inv = 1.f / c;
      sums[lane*4+0] *= inv; sums[lane*4+1] *= inv; sums[lane*4+2] *= inv;
    }
  }
  LDS_FENCE();

  // ---- subtract (chunked regs) ----
#pragma unroll
  for (int j = 0; j < CPT; ++j) {
    int s = (ids[j] - fid) * 4;
    f[j * 3 + 0] -= sums[s + 0];
    f[j * 3 + 1] -= sums[s + 1];
    f[j * 3 + 2] -= sums[s + 2];
  }

  // ---- repack: chunked b128 LDS writes into 28-word rows (conflict-free:
  //      phase quad-banks (j - l) % 8 all distinct) ----
#pragma unroll
  for (int j = 0; j < 6; ++j)
    *reinterpret_cast<float4*>(&obuf[lane * ROWW + 4 * j]) =
        make_float4(f[4*j+0], f[4*j+1], f[4*j+2], f[4*j+3]);
  LDS_FENCE();

  // ---- dense b128 reads + NON-TEMPORAL dense stores (16 full lines/instr) --
  f32x4* ov = reinterpret_cast<f32x4*>(out + cs * 3);
#pragma unroll
  for (int j = 0; j < 6; ++j) {
    int wl = 256 * j + 4 * lane;        // logical flat word
    int sl = wl / 24;                   // source lane (const-div -> magic mul)
    int m  = wl - sl * 24;              // word offset within row (mult of 4)
    f32x4 v = *reinterpret_cast<const f32x4*>(&obuf[sl * ROWW + m]);
    __builtin_nontemporal_store(v, &ov[64 * j + lane]);
  }
}

extern "C" void kernel_launch(void* const* d_in, const int* in_sizes, int n_in,
                              void* d_out, int out_size, void* d_ws, size_t ws_size,
                              hipStream_t stream) {
  const float* x = (const float*)d_in[0];
  const int* gb = (const int*)d_in[1];
  float* out = (float*)d_out;
  const int n = in_sizes[0] / 3;  // atoms

  long long nchunks = ((long long)n + WCHUNK - 1) / WCHUNK;
  int blocks = (int)((nchunks + WPB - 1) / WPB);
  fused_center_kernel<<<blocks, TPB, 0, stream>>>(x, gb, out, n);
}